// Round 5
// baseline (679.073 us; speedup 1.0000x reference)
//
#include <hip/hip_runtime.h>
#include <cmath>

#define CTXL 50
#define NC 300    // NCOND
#define NH 256    // NHID
#define NT 256    // threads per block
#define KPAD 320  // K padded to 10 k-steps of 32
#define ASTR 328  // LDS A row stride in shorts (656 B)
#define MROWS 64  // K1: emb rows per block
#define TSTR 264  // K1: transpose-staging stride in shorts (528 B)

typedef float  f32x4 __attribute__((ext_vector_type(4)));
typedef short  s16x8 __attribute__((ext_vector_type(8)));
typedef unsigned int u32x4 __attribute__((ext_vector_type(4)));

__device__ __forceinline__ ushort f2bf(float f) {
    unsigned u = __float_as_uint(f);
    unsigned r = (u + 0x7FFFu + ((u >> 16) & 1u)) >> 16;   // RNE
    return (ushort)r;
}
__device__ __forceinline__ float bf2f(ushort u) {
    return __uint_as_float(((unsigned)u) << 16);
}
__device__ __forceinline__ void nt_store16(ushort* p, s16x8 v) {
    __builtin_nontemporal_store(*(const u32x4*)&v, (u32x4*)p);
}

// ---------------------------------------------------------------------------
// prepass: W1 [300][256] -> W1T bf16 [256][320]; W2 [256][300] -> W2T bf16 [300][256]
__global__ void convert_w(const float* __restrict__ W1, const float* __restrict__ W2,
                          ushort* __restrict__ W1T, ushort* __restrict__ W2T) {
    const int t  = threadIdx.x;
    const int bi = blockIdx.x;
    if (bi < KPAD) {
        W1T[(size_t)t * KPAD + bi] = (bi < NC) ? f2bf(W1[(size_t)bi * NH + t]) : (ushort)0;
    } else {
        const int j = bi - KPAD;           // < 300
        W2T[(size_t)j * NH + t] = f2bf(W2[(size_t)t * NC + j]);
    }
}

// ---------------------------------------------------------------------------
// K1: H[ntok][256] bf16 = relu(embs @ W1 + b1). Contiguous streaming, MFMA.
// One block = 64 consecutive emb rows; 4 waves own 64 output cols each.
__global__ __launch_bounds__(NT, 3)
void k1_hidden(const float* __restrict__ embs,
               const float* __restrict__ b1,
               const ushort* __restrict__ W1T,
               ushort* __restrict__ H, int ntok) {
    __shared__ short A[MROWS * ASTR];      // 41984 B
    const int m0   = blockIdx.x * MROWS;
    const int tid  = threadIdx.x;
    const int wave = tid >> 6;
    const int lane = tid & 63;
    const int l15  = lane & 15;
    const int lhi  = lane >> 4;

    // stage 64 rows fp32 -> bf16 LDS (coalesced, chunk-major)
    #pragma unroll
    for (int i = 0; i < MROWS * 40 / NT; ++i) {     // 10 iters
        const int g = tid + NT * i;
        const int r = g / 40;
        const int c = g - r * 40;                    // 16B chunk 0..39
        int row = m0 + r; if (row >= ntok) row = ntok - 1;
        const float* src = embs + (size_t)row * NC + c * 8;
        float v[8];
        if (c < 37) {
            const float4 a0 = *(const float4*)src;
            const float4 a1 = *(const float4*)(src + 4);
            v[0]=a0.x; v[1]=a0.y; v[2]=a0.z; v[3]=a0.w;
            v[4]=a1.x; v[5]=a1.y; v[6]=a1.z; v[7]=a1.w;
        } else if (c == 37) {
            const float4 a0 = *(const float4*)src;
            v[0]=a0.x; v[1]=a0.y; v[2]=a0.z; v[3]=a0.w;
            v[4]=v[5]=v[6]=v[7]=0.0f;
        } else {
            #pragma unroll
            for (int q = 0; q < 8; ++q) v[q] = 0.0f;
        }
        s16x8 p;
        #pragma unroll
        for (int q = 0; q < 8; ++q) p[q] = (short)f2bf(v[q]);
        *(s16x8*)((char*)A + (size_t)r * (ASTR * 2) + c * 16) = p;
    }
    __syncthreads();

    f32x4 acc[4][4];
    #pragma unroll
    for (int mt = 0; mt < 4; ++mt)
        #pragma unroll
        for (int nt = 0; nt < 4; ++nt)
            acc[mt][nt] = (f32x4){0.f, 0.f, 0.f, 0.f};

    int abyte[4];
    #pragma unroll
    for (int mt = 0; mt < 4; ++mt)
        abyte[mt] = (mt * 16 + l15) * (ASTR * 2) + lhi * 16;
    const ushort* wb = W1T + (size_t)(wave * 64 + l15) * KPAD + lhi * 8;

    #pragma unroll
    for (int ks = 0; ks < KPAD / 32; ++ks) {
        s16x8 af[4], bfr[4];
        #pragma unroll
        for (int mt = 0; mt < 4; ++mt)
            af[mt] = *(const s16x8*)((const char*)A + abyte[mt] + ks * 64);
        #pragma unroll
        for (int nt = 0; nt < 4; ++nt)
            bfr[nt] = *(const s16x8*)(wb + nt * 16 * KPAD + ks * 32);
        #pragma unroll
        for (int mt = 0; mt < 4; ++mt)
            #pragma unroll
            for (int nt = 0; nt < 4; ++nt)
                acc[mt][nt] = __builtin_amdgcn_mfma_f32_16x16x32_bf16(
                    af[mt], bfr[nt], acc[mt][nt], 0, 0, 0);
    }

    // relu+bias -> bf16 transpose-stage in LDS (reuse A), then coalesced nt-store
    __syncthreads();                        // all A reads done
    short* T = A;                           // [64][TSTR] shorts
    #pragma unroll
    for (int nt = 0; nt < 4; ++nt) {
        const int col = wave * 64 + nt * 16 + l15;
        const float bb = b1[col];
        #pragma unroll
        for (int mt = 0; mt < 4; ++mt)
            #pragma unroll
            for (int q = 0; q < 4; ++q) {
                const int row = mt * 16 + lhi * 4 + q;   // C/D: col=l15, row=4*lhi+q
                T[row * TSTR + col] = (short)f2bf(fmaxf(acc[mt][nt][q] + bb, 0.0f));
            }
    }
    __syncthreads();
    #pragma unroll
    for (int i = 0; i < MROWS * 32 / NT; ++i) {     // 8 iters, 8-short chunks
        const int g  = tid + NT * i;
        const int r  = g >> 5;
        const int c8 = g & 31;
        const int row = m0 + r;
        if (row < ntok) {
            const s16x8 val = *(const s16x8*)((const char*)T + r * (TSTR * 2) + c8 * 16);
            nt_store16(H + (size_t)row * NH + c8 * 8, val);
        }
    }
}

// ---------------------------------------------------------------------------
// K2: out[b] = sigmoid(mean_l H[ctx[b,l]] @ W2 + b2) * embs[x[b]]
// thread = column; 50 coalesced bf16 loads, in-register mean, GEMV epilogue.
__global__ __launch_bounds__(NT, 8)
void k2_pool(const int* __restrict__ x,
             const int* __restrict__ ctx,
             const float* __restrict__ embs,
             const ushort* __restrict__ H,
             const ushort* __restrict__ W2T,
             const float* __restrict__ b2,
             float* __restrict__ out) {
    __shared__ int   ctxs[CTXL];
    __shared__ float pooled[NH];
    const int b   = blockIdx.x;
    const int tid = threadIdx.x;

    if (tid < CTXL) ctxs[tid] = ctx[b * CTXL + tid];
    __syncthreads();

    float s0 = 0.0f, s1 = 0.0f;
    #pragma unroll
    for (int l = 0; l < CTXL; l += 2) {
        s0 += bf2f(H[(size_t)ctxs[l]     * NH + tid]);
        s1 += bf2f(H[(size_t)ctxs[l + 1] * NH + tid]);
    }
    pooled[tid] = (s0 + s1) * (1.0f / CTXL);
    __syncthreads();

    const int xrow = x[b];
    for (int j = tid; j < NC; j += NT) {
        float s = b2[j];
        const s16x8* wrow = (const s16x8*)(W2T + (size_t)j * NH);
        #pragma unroll
        for (int c = 0; c < NH / 8; ++c) {
            const s16x8 w8 = wrow[c];
            const float4 p0 = *(const float4*)(&pooled[c * 8]);
            const float4 p1 = *(const float4*)(&pooled[c * 8 + 4]);
            s = fmaf(p0.x, bf2f((ushort)w8[0]), s);
            s = fmaf(p0.y, bf2f((ushort)w8[1]), s);
            s = fmaf(p0.z, bf2f((ushort)w8[2]), s);
            s = fmaf(p0.w, bf2f((ushort)w8[3]), s);
            s = fmaf(p1.x, bf2f((ushort)w8[4]), s);
            s = fmaf(p1.y, bf2f((ushort)w8[5]), s);
            s = fmaf(p1.z, bf2f((ushort)w8[6]), s);
            s = fmaf(p1.w, bf2f((ushort)w8[7]), s);
        }
        const float g = 1.0f / (1.0f + __expf(-s));
        out[(size_t)b * NC + j] = g * embs[(size_t)xrow * NC + j];
    }
}

// ---------------------------------------------------------------------------
// fallback (round-2-proven structure): fused per-sample kernel, fp32 gather
__global__ __launch_bounds__(NT, 4)
void esa_fallback(const int* __restrict__ x, const int* __restrict__ ctx,
                  const float* __restrict__ embs, const float* __restrict__ b1,
                  const float* __restrict__ b2, const ushort* __restrict__ W1T,
                  const ushort* __restrict__ W2T, float* __restrict__ out) {
    __shared__ short A[CTXL * ASTR];
    __shared__ float xemb[NC];
    __shared__ float pooled[NH];
    const int b = blockIdx.x, tid = threadIdx.x;
    const int wave = tid >> 6, lane = tid & 63, l15 = lane & 15, lhi = lane >> 4;

    const int r = tid >> 2, cq = tid & 3;
    if (r < CTXL) {
        const int row = ctx[b * CTXL + r];
        const float* src = embs + (size_t)row * NC;
        #pragma unroll
        for (int i = 0; i < 19; ++i) {
            const int c = cq + 4 * i;
            if (c < 75) {
                const float4 v = *(const float4*)(src + c * 4);
                uint2 p;
                p.x = (unsigned)f2bf(v.x) | ((unsigned)f2bf(v.y) << 16);
                p.y = (unsigned)f2bf(v.z) | ((unsigned)f2bf(v.w) << 16);
                *(uint2*)((char*)A + (size_t)r * (ASTR * 2) + c * 8) = p;
            }
        }
        #pragma unroll
        for (int k = cq; k < 5; k += 4)
            *(uint2*)((char*)A + (size_t)r * (ASTR * 2) + 600 + k * 8) = make_uint2(0u, 0u);
    }
    { const int row = x[b];
      if (tid < NC / 4) ((float4*)xemb)[tid] = ((const float4*)(embs + (size_t)row * NC))[tid]; }
    __syncthreads();

    f32x4 acc[4][4];
    #pragma unroll
    for (int mt = 0; mt < 4; ++mt)
        #pragma unroll
        for (int nt = 0; nt < 4; ++nt) acc[mt][nt] = (f32x4){0.f, 0.f, 0.f, 0.f};
    int abyte[4];
    #pragma unroll
    for (int mt = 0; mt < 4; ++mt) {
        int rr = mt * 16 + l15; if (rr >= CTXL) rr = 0;
        abyte[mt] = rr * (ASTR * 2) + lhi * 16;
    }
    const ushort* wb = W1T + (size_t)(wave * 64 + l15) * KPAD + lhi * 8;
    #pragma unroll
    for (int ks = 0; ks < KPAD / 32; ++ks) {
        s16x8 af[4], bfr[4];
        #pragma unroll
        for (int mt = 0; mt < 4; ++mt)
            af[mt] = *(const s16x8*)((const char*)A + abyte[mt] + ks * 64);
        #pragma unroll
        for (int nt = 0; nt < 4; ++nt)
            bfr[nt] = *(const s16x8*)(wb + nt * 16 * KPAD + ks * 32);
        #pragma unroll
        for (int mt = 0; mt < 4; ++mt)
            #pragma unroll
            for (int nt = 0; nt < 4; ++nt)
                acc[mt][nt] = __builtin_amdgcn_mfma_f32_16x16x32_bf16(
                    af[mt], bfr[nt], acc[mt][nt], 0, 0, 0);
    }
    #pragma unroll
    for (int nt = 0; nt < 4; ++nt) {
        const float bb = b1[wave * 64 + nt * 16 + l15];
        float s = 0.0f;
        #pragma unroll
        for (int mt = 0; mt < 4; ++mt)
            #pragma unroll
            for (int q = 0; q < 4; ++q) {
                const int row = mt * 16 + lhi * 4 + q;
                const float v = fmaxf(acc[mt][nt][q] + bb, 0.0f);
                s += (row < CTXL) ? v : 0.0f;
            }
        s += __shfl_xor(s, 16);
        s += __shfl_xor(s, 32);
        if (lhi == 0) pooled[wave * 64 + nt * 16 + l15] = s * (1.0f / CTXL);
    }
    __syncthreads();
    for (int j = tid; j < NC; j += NT) {
        float s = b2[j];
        const s16x8* wrow = (const s16x8*)(W2T + (size_t)j * NH);
        #pragma unroll
        for (int c = 0; c < NH / 8; ++c) {
            const s16x8 w8 = wrow[c];
            const float4 p0 = *(const float4*)(&pooled[c * 8]);
            const float4 p1 = *(const float4*)(&pooled[c * 8 + 4]);
            s = fmaf(p0.x, bf2f((ushort)w8[0]), s);
            s = fmaf(p0.y, bf2f((ushort)w8[1]), s);
            s = fmaf(p0.z, bf2f((ushort)w8[2]), s);
            s = fmaf(p0.w, bf2f((ushort)w8[3]), s);
            s = fmaf(p1.x, bf2f((ushort)w8[4]), s);
            s = fmaf(p1.y, bf2f((ushort)w8[5]), s);
            s = fmaf(p1.z, bf2f((ushort)w8[6]), s);
            s = fmaf(p1.w, bf2f((ushort)w8[7]), s);
        }
        const float g = 1.0f / (1.0f + __expf(-s));
        out[(size_t)b * NC + j] = g * xemb[j];
    }
}

extern "C" void kernel_launch(void* const* d_in, const int* in_sizes, int n_in,
                              void* d_out, int out_size, void* d_ws, size_t ws_size,
                              hipStream_t stream) {
    const int*   x    = (const int*)d_in[0];
    const int*   ctx  = (const int*)d_in[1];
    const float* embs = (const float*)d_in[2];
    const float* W1   = (const float*)d_in[3];
    const float* b1   = (const float*)d_in[4];
    const float* W2   = (const float*)d_in[5];
    const float* b2   = (const float*)d_in[6];
    float* out = (float*)d_out;

    const int B    = in_sizes[0];
    const int ntok = in_sizes[2] / NC;

    const size_t h_bytes   = (size_t)ntok * NH * 2;   // 51.2 MB
    const size_t w1t_bytes = (size_t)NH * KPAD * 2;   // 160 KB
    const size_t w2t_bytes = (size_t)NC * NH * 2;     // 150 KB

    if (ws_size >= h_bytes + w1t_bytes + w2t_bytes) {
        ushort* H   = (ushort*)d_ws;
        ushort* W1T = (ushort*)((char*)d_ws + h_bytes);
        ushort* W2T = (ushort*)((char*)d_ws + h_bytes + w1t_bytes);
        convert_w<<<KPAD + NC, NT, 0, stream>>>(W1, W2, W1T, W2T);
        k1_hidden<<<(ntok + MROWS - 1) / MROWS, NT, 0, stream>>>(embs, b1, W1T, H, ntok);
        k2_pool<<<B, NT, 0, stream>>>(x, ctx, embs, H, W2T, b2, out);
    } else {
        ushort* W1T = (ushort*)d_ws;
        ushort* W2T = (ushort*)((char*)d_ws + w1t_bytes);
        convert_w<<<KPAD + NC, NT, 0, stream>>>(W1, W2, W1T, W2T);
        esa_fallback<<<B, NT, 0, stream>>>(x, ctx, embs, b1, b2, W1T, W2T, out);
    }
}

// Round 6
// 157.719 us; speedup vs baseline: 4.3056x; 4.3056x over previous
//
#include <hip/hip_runtime.h>
#include <cmath>

#define CTXL 50
#define NC 300    // NCOND
#define NH 256    // NHID
#define NT 256    // threads per block
#define KPAD 320  // K padded to 10 k-steps of 32
#define ASTR 328  // LDS A row stride in shorts (656 B)
#define MROWS 64  // K1: emb rows per block
#define TSTR 264  // K1: transpose-staging stride in shorts (528 B)

typedef float  f32x4 __attribute__((ext_vector_type(4)));
typedef short  s16x8 __attribute__((ext_vector_type(8)));
typedef short  s16x4 __attribute__((ext_vector_type(4)));

__device__ __forceinline__ ushort f2bf(float f) {
    unsigned u = __float_as_uint(f);
    unsigned r = (u + 0x7FFFu + ((u >> 16) & 1u)) >> 16;   // RNE
    return (ushort)r;
}
__device__ __forceinline__ float bf2f(ushort u) {
    return __uint_as_float(((unsigned)u) << 16);
}

// ---------------------------------------------------------------------------
// prepass: W1 [300][256] -> W1T bf16 [256][320]; W2 [256][300] -> W2T bf16 [300][256]
__global__ void convert_w(const float* __restrict__ W1, const float* __restrict__ W2,
                          ushort* __restrict__ W1T, ushort* __restrict__ W2T) {
    const int t  = threadIdx.x;
    const int bi = blockIdx.x;
    if (bi < KPAD) {
        W1T[(size_t)t * KPAD + bi] = (bi < NC) ? f2bf(W1[(size_t)bi * NH + t]) : (ushort)0;
    } else {
        const int j = bi - KPAD;           // < 300
        W2T[(size_t)j * NH + t] = f2bf(W2[(size_t)t * NC + j]);
    }
}

// ---------------------------------------------------------------------------
// K1: H[ntok][256] bf16 = relu(embs @ W1 + b1). Contiguous streaming, MFMA.
// One block = 64 consecutive emb rows; 4 waves own 64 output cols each.
// Regular stores (NOT non-temporal): H should stay L3-resident for K2.
__global__ __launch_bounds__(NT, 3)
void k1_hidden(const float* __restrict__ embs,
               const float* __restrict__ b1,
               const ushort* __restrict__ W1T,
               ushort* __restrict__ H, int ntok) {
    __shared__ short A[MROWS * ASTR];      // 41984 B
    const int m0   = blockIdx.x * MROWS;
    const int tid  = threadIdx.x;
    const int wave = tid >> 6;
    const int lane = tid & 63;
    const int l15  = lane & 15;
    const int lhi  = lane >> 4;

    // stage 64 rows fp32 -> bf16 LDS (coalesced, chunk-major)
    #pragma unroll
    for (int i = 0; i < MROWS * 40 / NT; ++i) {     // 10 iters
        const int g = tid + NT * i;
        const int r = g / 40;
        const int c = g - r * 40;                    // 16B chunk 0..39
        int row = m0 + r; if (row >= ntok) row = ntok - 1;
        const float* src = embs + (size_t)row * NC + c * 8;
        float v[8];
        if (c < 37) {
            const float4 a0 = *(const float4*)src;
            const float4 a1 = *(const float4*)(src + 4);
            v[0]=a0.x; v[1]=a0.y; v[2]=a0.z; v[3]=a0.w;
            v[4]=a1.x; v[5]=a1.y; v[6]=a1.z; v[7]=a1.w;
        } else if (c == 37) {
            const float4 a0 = *(const float4*)src;
            v[0]=a0.x; v[1]=a0.y; v[2]=a0.z; v[3]=a0.w;
            v[4]=v[5]=v[6]=v[7]=0.0f;
        } else {
            #pragma unroll
            for (int q = 0; q < 8; ++q) v[q] = 0.0f;
        }
        s16x8 p;
        #pragma unroll
        for (int q = 0; q < 8; ++q) p[q] = (short)f2bf(v[q]);
        *(s16x8*)((char*)A + (size_t)r * (ASTR * 2) + c * 16) = p;
    }
    __syncthreads();

    f32x4 acc[4][4];
    #pragma unroll
    for (int mt = 0; mt < 4; ++mt)
        #pragma unroll
        for (int nt = 0; nt < 4; ++nt)
            acc[mt][nt] = (f32x4){0.f, 0.f, 0.f, 0.f};

    int abyte[4];
    #pragma unroll
    for (int mt = 0; mt < 4; ++mt)
        abyte[mt] = (mt * 16 + l15) * (ASTR * 2) + lhi * 16;
    const ushort* wb = W1T + (size_t)(wave * 64 + l15) * KPAD + lhi * 8;

    #pragma unroll
    for (int ks = 0; ks < KPAD / 32; ++ks) {
        s16x8 af[4], bfr[4];
        #pragma unroll
        for (int mt = 0; mt < 4; ++mt)
            af[mt] = *(const s16x8*)((const char*)A + abyte[mt] + ks * 64);
        #pragma unroll
        for (int nt = 0; nt < 4; ++nt)
            bfr[nt] = *(const s16x8*)(wb + nt * 16 * KPAD + ks * 32);
        #pragma unroll
        for (int mt = 0; mt < 4; ++mt)
            #pragma unroll
            for (int nt = 0; nt < 4; ++nt)
                acc[mt][nt] = __builtin_amdgcn_mfma_f32_16x16x32_bf16(
                    af[mt], bfr[nt], acc[mt][nt], 0, 0, 0);
    }

    // relu+bias -> bf16 transpose-stage in LDS (reuse A), then coalesced store
    __syncthreads();                        // all A reads done
    short* T = A;                           // [64][TSTR] shorts
    #pragma unroll
    for (int nt = 0; nt < 4; ++nt) {
        const int col = wave * 64 + nt * 16 + l15;
        const float bb = b1[col];
        #pragma unroll
        for (int mt = 0; mt < 4; ++mt)
            #pragma unroll
            for (int q = 0; q < 4; ++q) {
                const int row = mt * 16 + lhi * 4 + q;   // C/D: col=l15, row=4*lhi+q
                T[row * TSTR + col] = (short)f2bf(fmaxf(acc[mt][nt][q] + bb, 0.0f));
            }
    }
    __syncthreads();
    #pragma unroll
    for (int i = 0; i < MROWS * 32 / NT; ++i) {     // 8 iters, 8-short chunks
        const int g  = tid + NT * i;
        const int r  = g >> 5;
        const int c8 = g & 31;
        const int row = m0 + r;
        if (row < ntok)
            *(s16x8*)(H + (size_t)row * NH + c8 * 8) =
                *(const s16x8*)((const char*)T + r * (TSTR * 2) + c8 * 16);
    }
}

// ---------------------------------------------------------------------------
// K2: out[b] = sigmoid(mean_l H[ctx[b,l]] @ W2 + b2) * embs[x[b]]
// Wave w owns rows [l0,l0+cnt); lane owns 4 contiguous cols (ushort4 loads,
// one full 512B H row per wave per step). Small live set -> no spills.
__global__ __launch_bounds__(NT, 4)
void k2_pool(const int* __restrict__ x,
             const int* __restrict__ ctx,
             const float* __restrict__ embs,
             const ushort* __restrict__ H,
             const ushort* __restrict__ W2T,
             const float* __restrict__ b2,
             float* __restrict__ out) {
    __shared__ int   ctxs[CTXL];
    __shared__ float pool4[4][NH];
    __shared__ float pooled[NH];
    const int b    = threadIdx.y + blockIdx.x * blockDim.y;  // blockDim.y==1
    const int tid  = threadIdx.x;
    const int wave = tid >> 6;
    const int lane = tid & 63;

    if (tid < CTXL) ctxs[tid] = ctx[b * CTXL + tid];
    __syncthreads();

    // rows split 13/13/12/12 across waves
    const int l0  = (wave < 2) ? 13 * wave : 26 + 12 * (wave - 2);
    const int cnt = (wave < 2) ? 13 : 12;

    float4 ps = make_float4(0.f, 0.f, 0.f, 0.f);
    #pragma unroll 13
    for (int i = 0; i < 13; ++i) {
        if (i < cnt) {
            const int row = ctxs[l0 + i];
            const s16x4 h4 = *(const s16x4*)(H + (size_t)row * NH + lane * 4);
            ps.x += bf2f((ushort)h4[0]);
            ps.y += bf2f((ushort)h4[1]);
            ps.z += bf2f((ushort)h4[2]);
            ps.w += bf2f((ushort)h4[3]);
        }
    }
    *(float4*)(&pool4[wave][lane * 4]) = ps;
    __syncthreads();

    pooled[tid] = (pool4[0][tid] + pool4[1][tid] +
                   pool4[2][tid] + pool4[3][tid]) * (1.0f / CTXL);
    __syncthreads();

    const int xrow = x[b];
    for (int j = tid; j < NC; j += NT) {
        float s = b2[j];
        const s16x8* wrow = (const s16x8*)(W2T + (size_t)j * NH);
        #pragma unroll 8
        for (int c = 0; c < NH / 8; ++c) {
            const s16x8 w8 = wrow[c];
            const float4 p0 = *(const float4*)(&pooled[c * 8]);
            const float4 p1 = *(const float4*)(&pooled[c * 8 + 4]);
            s = fmaf(p0.x, bf2f((ushort)w8[0]), s);
            s = fmaf(p0.y, bf2f((ushort)w8[1]), s);
            s = fmaf(p0.z, bf2f((ushort)w8[2]), s);
            s = fmaf(p0.w, bf2f((ushort)w8[3]), s);
            s = fmaf(p1.x, bf2f((ushort)w8[4]), s);
            s = fmaf(p1.y, bf2f((ushort)w8[5]), s);
            s = fmaf(p1.z, bf2f((ushort)w8[6]), s);
            s = fmaf(p1.w, bf2f((ushort)w8[7]), s);
        }
        const float g = 1.0f / (1.0f + __expf(-s));
        out[(size_t)b * NC + j] = g * embs[(size_t)xrow * NC + j];
    }
}

// ---------------------------------------------------------------------------
// fallback (round-2-proven structure): fused per-sample kernel, fp32 gather
__global__ __launch_bounds__(NT, 4)
void esa_fallback(const int* __restrict__ x, const int* __restrict__ ctx,
                  const float* __restrict__ embs, const float* __restrict__ b1,
                  const float* __restrict__ b2, const ushort* __restrict__ W1T,
                  const ushort* __restrict__ W2T, float* __restrict__ out) {
    __shared__ short A[CTXL * ASTR];
    __shared__ float xemb[NC];
    __shared__ float pooled[NH];
    const int b = blockIdx.x, tid = threadIdx.x;
    const int wave = tid >> 6, lane = tid & 63, l15 = lane & 15, lhi = lane >> 4;

    const int r = tid >> 2, cq = tid & 3;
    if (r < CTXL) {
        const int row = ctx[b * CTXL + r];
        const float* src = embs + (size_t)row * NC;
        #pragma unroll
        for (int i = 0; i < 19; ++i) {
            const int c = cq + 4 * i;
            if (c < 75) {
                const float4 v = *(const float4*)(src + c * 4);
                uint2 p;
                p.x = (unsigned)f2bf(v.x) | ((unsigned)f2bf(v.y) << 16);
                p.y = (unsigned)f2bf(v.z) | ((unsigned)f2bf(v.w) << 16);
                *(uint2*)((char*)A + (size_t)r * (ASTR * 2) + c * 8) = p;
            }
        }
        #pragma unroll
        for (int k = cq; k < 5; k += 4)
            *(uint2*)((char*)A + (size_t)r * (ASTR * 2) + 600 + k * 8) = make_uint2(0u, 0u);
    }
    { const int row = x[b];
      if (tid < NC / 4) ((float4*)xemb)[tid] = ((const float4*)(embs + (size_t)row * NC))[tid]; }
    __syncthreads();

    f32x4 acc[4][4];
    #pragma unroll
    for (int mt = 0; mt < 4; ++mt)
        #pragma unroll
        for (int nt = 0; nt < 4; ++nt) acc[mt][nt] = (f32x4){0.f, 0.f, 0.f, 0.f};
    int abyte[4];
    #pragma unroll
    for (int mt = 0; mt < 4; ++mt) {
        int rr = mt * 16 + l15; if (rr >= CTXL) rr = 0;
        abyte[mt] = rr * (ASTR * 2) + lhi * 16;
    }
    const ushort* wb = W1T + (size_t)(wave * 64 + l15) * KPAD + lhi * 8;
    #pragma unroll
    for (int ks = 0; ks < KPAD / 32; ++ks) {
        s16x8 af[4], bfr[4];
        #pragma unroll
        for (int mt = 0; mt < 4; ++mt)
            af[mt] = *(const s16x8*)((const char*)A + abyte[mt] + ks * 64);
        #pragma unroll
        for (int nt = 0; nt < 4; ++nt)
            bfr[nt] = *(const s16x8*)(wb + nt * 16 * KPAD + ks * 32);
        #pragma unroll
        for (int mt = 0; mt < 4; ++mt)
            #pragma unroll
            for (int nt = 0; nt < 4; ++nt)
                acc[mt][nt] = __builtin_amdgcn_mfma_f32_16x16x32_bf16(
                    af[mt], bfr[nt], acc[mt][nt], 0, 0, 0);
    }
    #pragma unroll
    for (int nt = 0; nt < 4; ++nt) {
        const float bb = b1[wave * 64 + nt * 16 + l15];
        float s = 0.0f;
        #pragma unroll
        for (int mt = 0; mt < 4; ++mt)
            #pragma unroll
            for (int q = 0; q < 4; ++q) {
                const int row = mt * 16 + lhi * 4 + q;
                const float v = fmaxf(acc[mt][nt][q] + bb, 0.0f);
                s += (row < CTXL) ? v : 0.0f;
            }
        s += __shfl_xor(s, 16);
        s += __shfl_xor(s, 32);
        if (lhi == 0) pooled[wave * 64 + nt * 16 + l15] = s * (1.0f / CTXL);
    }
    __syncthreads();
    for (int j = tid; j < NC; j += NT) {
        float s = b2[j];
        const s16x8* wrow = (const s16x8*)(W2T + (size_t)j * NH);
        #pragma unroll 8
        for (int c = 0; c < NH / 8; ++c) {
            const s16x8 w8 = wrow[c];
            const float4 p0 = *(const float4*)(&pooled[c * 8]);
            const float4 p1 = *(const float4*)(&pooled[c * 8 + 4]);
            s = fmaf(p0.x, bf2f((ushort)w8[0]), s);
            s = fmaf(p0.y, bf2f((ushort)w8[1]), s);
            s = fmaf(p0.z, bf2f((ushort)w8[2]), s);
            s = fmaf(p0.w, bf2f((ushort)w8[3]), s);
            s = fmaf(p1.x, bf2f((ushort)w8[4]), s);
            s = fmaf(p1.y, bf2f((ushort)w8[5]), s);
            s = fmaf(p1.z, bf2f((ushort)w8[6]), s);
            s = fmaf(p1.w, bf2f((ushort)w8[7]), s);
        }
        const float g = 1.0f / (1.0f + __expf(-s));
        out[(size_t)b * NC + j] = g * xemb[j];
    }
}

extern "C" void kernel_launch(void* const* d_in, const int* in_sizes, int n_in,
                              void* d_out, int out_size, void* d_ws, size_t ws_size,
                              hipStream_t stream) {
    const int*   x    = (const int*)d_in[0];
    const int*   ctx  = (const int*)d_in[1];
    const float* embs = (const float*)d_in[2];
    const float* W1   = (const float*)d_in[3];
    const float* b1   = (const float*)d_in[4];
    const float* W2   = (const float*)d_in[5];
    const float* b2   = (const float*)d_in[6];
    float* out = (float*)d_out;

    const int B    = in_sizes[0];
    const int ntok = in_sizes[2] / NC;

    const size_t h_bytes   = (size_t)ntok * NH * 2;   // 51.2 MB
    const size_t w1t_bytes = (size_t)NH * KPAD * 2;   // 160 KB
    const size_t w2t_bytes = (size_t)NC * NH * 2;     // 150 KB

    if (ws_size >= h_bytes + w1t_bytes + w2t_bytes) {
        ushort* H   = (ushort*)d_ws;
        ushort* W1T = (ushort*)((char*)d_ws + h_bytes);
        ushort* W2T = (ushort*)((char*)d_ws + h_bytes + w1t_bytes);
        convert_w<<<KPAD + NC, NT, 0, stream>>>(W1, W2, W1T, W2T);
        k1_hidden<<<(ntok + MROWS - 1) / MROWS, NT, 0, stream>>>(embs, b1, W1T, H, ntok);
        dim3 blk(NT, 1, 1);
        k2_pool<<<B, blk, 0, stream>>>(x, ctx, embs, H, W2T, b2, out);
    } else {
        ushort* W1T = (ushort*)d_ws;
        ushort* W2T = (ushort*)((char*)d_ws + w1t_bytes);
        convert_w<<<KPAD + NC, NT, 0, stream>>>(W1, W2, W1T, W2T);
        esa_fallback<<<B, NT, 0, stream>>>(x, ctx, embs, b1, b2, W1T, W2T, out);
    }
}